// Round 4
// baseline (156.091 us; speedup 1.0000x reference)
//
#include <hip/hip_runtime.h>
#include <hip/hip_bf16.h>

#define CIN 32
#define OCH 64
#define HH  256
#define WW  256
#define HW  (HH * WW)
#define BH  8                 // output rows per block
#define ROWB (258 * CIN * 2)  // 16512 B per LDS row-slot

typedef __bf16 bf16x8 __attribute__((ext_vector_type(8)));
typedef float  f32x4  __attribute__((ext_vector_type(4)));

// Fused 3x3 conv (implicit GEMM, bf16 MFMA), sliding window over h.
// Wave partition: wave owns 8 w-tiles (nt) x 32 output channels (2 o-groups),
// so each LDS B-fragment is read by only 2 waves (was 4) -> LDS pipe off the
// critical path. Weights register-resident (72 VGPR), bias folded into acc.
// LDS row-slot: w-entry wp (= w+1) is 64 B = 4 chunks of 8 channels; chunk for
// channels sc*8..+7 at slot sc ^ ((w>>1)&3). Writes <=2-way (free); B-reads
// conflict-free (enumerated).
__global__ __launch_bounds__(256, 2) void conv_fused_kernel(
        const float* __restrict__ x, const float* __restrict__ wgt,
        const float* __restrict__ bias, float* __restrict__ out) {
    // chunked XCD swizzle: 512 blocks, each XCD gets 64 consecutive nids
    // (2 full batches) so h-adjacent tiles share halo rows in one L2.
    const int bid = blockIdx.x;
    const int nid = (bid & 7) * 64 + (bid >> 3);
    const int b   = nid >> 5;                    // 0..15
    const int h0  = (nid & 31) * BH;             // 0..248
    const int tid = threadIdx.x;
    const int l   = tid & 63, wid = tid >> 6;
    const int lm  = l & 15,  lh  = l >> 4;
    const int ogb = (wid & 1) * 2;               // o-group base: {0,1} or {2,3}
    const int ntb = (wid >> 1) * 8;              // w-tile base: 0 or 8

    __shared__ __bf16 xs[4][258][CIN];           // 66,048 B ring of 4 row-slots
    char* lds = (char*)&xs[0][0][0];
    const float* xb = x + (size_t)b * CIN * HW;

    // zero the w-pad entries (wp=0 and wp=257) of all 4 slots
    if (tid < 32) {
        const int s = tid >> 3, k = tid & 7;
        const int wp = (k < 4) ? 0 : 257;
        *(f32x4*)(lds + s * ROWB + wp * 64 + (k & 3) * 16) = (f32x4){0, 0, 0, 0};
    }

    // ---- weights inline (L2-hot): af[g][t][j] = w[(ogb+g)*16+lm][(lh*8+j)*9+t]
    bf16x8 af[2][9];
#pragma unroll
    for (int g = 0; g < 2; ++g) {
        const float* wp_ = wgt + (size_t)((ogb + g) * 16 + lm) * 288 + (size_t)lh * 8 * 9;
#pragma unroll
        for (int t = 0; t < 9; ++t)
#pragma unroll
            for (int j = 0; j < 8; ++j)
                af[g][t][j] = (__bf16)wp_[j * 9 + t];
    }
    float bv[2][4];
#pragma unroll
    for (int g = 0; g < 2; ++g)
#pragma unroll
        for (int r = 0; r < 4; ++r)
            bv[g][r] = bias[(ogb + g) * 16 + lh * 4 + r];

    // ---- full staging of one row (prologue)
    auto stage = [&](int row) {
        char* slot = lds + ((row + 1) & 3) * ROWB;
        if (row >= 0 && row < HH) {
            const float* rp = xb + (size_t)row * WW;
#pragma unroll
            for (int wh = 0; wh < 2; ++wh) {
                float2 v[8];
#pragma unroll
                for (int j = 0; j < 8; ++j)
                    v[j] = *(const float2*)(rp + (size_t)(wid * 8 + j) * HW + wh * 128 + 2 * l);
#pragma unroll
                for (int p = 0; p < 2; ++p) {
                    const int w = wh * 128 + 2 * l + p;
                    bf16x8 pk;
#pragma unroll
                    for (int j = 0; j < 8; ++j) pk[j] = (__bf16)(p ? v[j].y : v[j].x);
                    *(bf16x8*)(slot + (w + 1) * 64 + ((wid ^ ((w >> 1) & 3)) << 4)) = pk;
                }
            }
        } else {
#pragma unroll
            for (int wh = 0; wh < 2; ++wh)
#pragma unroll
                for (int p = 0; p < 2; ++p) {
                    const int w = wh * 128 + 2 * l + p;
                    *(f32x4*)(slot + (w + 1) * 64 + ((wid ^ ((w >> 1) & 3)) << 4)) =
                        (f32x4){0, 0, 0, 0};
                }
        }
    };

    stage(h0 - 1); stage(h0); stage(h0 + 1);

    // per-lane swizzled w-entry offsets for the 3 kw taps (nt-independent:
    // (nt*16)>>1 == 0 mod 4; u<0 hits the zero pad so any slot is fine)
    int off[3];
#pragma unroll
    for (int kw = 0; kw < 3; ++kw) {
        const int u = lm + kw - 1;
        const int m = (u < 0) ? 3 : ((u >> 1) & 3);
        off[kw] = (lm + kw) * 64 + ((lh ^ m) << 4);
    }

    __syncthreads();

    for (int i = 0; i < BH; ++i) {
        const int h  = h0 + i;
        const int nr = h + 2;
        const bool ldnext = (i < BH - 1) && (nr < HH);
        const bool zrnext = (i < BH - 1) && (nr >= HH);

        // T14 issue-early: global loads for row h+2 (consumed after compute)
        float2 v[16];
        if (ldnext) {
            const float* rp = xb + (size_t)nr * WW;
#pragma unroll
            for (int wh = 0; wh < 2; ++wh)
#pragma unroll
                for (int j = 0; j < 8; ++j)
                    v[wh * 8 + j] =
                        *(const float2*)(rp + (size_t)(wid * 8 + j) * HW + wh * 128 + 2 * l);
        }

        // ---- compute output row h from slots (h)&3,(h+1)&3,(h+2)&3
        const char* base[3] = { lds + ((h    ) & 3) * ROWB,
                                lds + ((h + 1) & 3) * ROWB,
                                lds + ((h + 2) & 3) * ROWB };
        f32x4 acc[8][2];
#pragma unroll
        for (int nt = 0; nt < 8; ++nt)
#pragma unroll
            for (int g = 0; g < 2; ++g)
                acc[nt][g] = (f32x4){bv[g][0], bv[g][1], bv[g][2], bv[g][3]};

#pragma unroll
        for (int nt = 0; nt < 8; ++nt)
#pragma unroll
            for (int kh = 0; kh < 3; ++kh)
#pragma unroll
                for (int kw = 0; kw < 3; ++kw) {
                    bf16x8 bf = *(const bf16x8*)(base[kh] + off[kw] + (ntb + nt) * 1024);
                    acc[nt][0] = __builtin_amdgcn_mfma_f32_16x16x32_bf16(
                        af[0][kh * 3 + kw], bf, acc[nt][0], 0, 0, 0);
                    acc[nt][1] = __builtin_amdgcn_mfma_f32_16x16x32_bf16(
                        af[1][kh * 3 + kw], bf, acc[nt][1], 0, 0, 0);
                }

        // ---- store row h (nontemporal: don't evict x from L2/L3)
        float* outb = out + (size_t)b * OCH * HW + (size_t)h * WW;
#pragma unroll
        for (int nt = 0; nt < 8; ++nt)
#pragma unroll
            for (int g = 0; g < 2; ++g)
#pragma unroll
                for (int r2 = 0; r2 < 4; ++r2)
                    __builtin_nontemporal_store(
                        acc[nt][g][r2],
                        &outb[(size_t)((ogb + g) * 16 + lh * 4 + r2) * HW +
                              (ntb + nt) * 16 + lm]);

        // ---- write-late: cvt + ds_write row h+2 into slot (h+3)&3
        if (ldnext) {
            char* slot = lds + ((nr + 1) & 3) * ROWB;
#pragma unroll
            for (int wh = 0; wh < 2; ++wh)
#pragma unroll
                for (int p = 0; p < 2; ++p) {
                    const int w = wh * 128 + 2 * l + p;
                    bf16x8 pk;
#pragma unroll
                    for (int j = 0; j < 8; ++j)
                        pk[j] = (__bf16)(p ? v[wh * 8 + j].y : v[wh * 8 + j].x);
                    *(bf16x8*)(slot + (w + 1) * 64 + ((wid ^ ((w >> 1) & 3)) << 4)) = pk;
                }
        } else if (zrnext) {
            char* slot = lds + ((nr + 1) & 3) * ROWB;
#pragma unroll
            for (int wh = 0; wh < 2; ++wh)
#pragma unroll
                for (int p = 0; p < 2; ++p) {
                    const int w = wh * 128 + 2 * l + p;
                    *(f32x4*)(slot + (w + 1) * 64 + ((wid ^ ((w >> 1) & 3)) << 4)) =
                        (f32x4){0, 0, 0, 0};
                }
        }
        if (i < BH - 1) __syncthreads();
    }
}

extern "C" void kernel_launch(void* const* d_in, const int* in_sizes, int n_in,
                              void* d_out, int out_size, void* d_ws, size_t ws_size,
                              hipStream_t stream) {
    const float* x    = (const float*)d_in[0];
    const float* w    = (const float*)d_in[1];
    const float* bias = (const float*)d_in[2];
    float* out = (float*)d_out;

    hipLaunchKernelGGL(conv_fused_kernel, dim3(16 * (HH / BH)), dim3(256), 0, stream,
                       x, w, bias, out);
}